// Round 1
// baseline (507.333 us; speedup 1.0000x reference)
//
#include <hip/hip_runtime.h>

#define FP8_MAX_F 448.0f

static constexpr int M = 8192;   // 4*2048
static constexpr int N = 8192;
static constexpr int K = 4096;

typedef __attribute__((ext_vector_type(4))) int i32x4;

// ---------------- amax reduction (exact, bit-trick atomicMax) ----------------
__global__ void amax_kernel(const float* __restrict__ x, long n4,
                            unsigned* __restrict__ out) {
    unsigned local = 0u;
    const long stride = (long)gridDim.x * blockDim.x;
    const float4* xv = (const float4*)x;
    for (long i = (long)blockIdx.x * blockDim.x + threadIdx.x; i < n4; i += stride) {
        float4 v = xv[i];
        unsigned a0 = __float_as_uint(v.x) & 0x7fffffffu;
        unsigned a1 = __float_as_uint(v.y) & 0x7fffffffu;
        unsigned a2 = __float_as_uint(v.z) & 0x7fffffffu;
        unsigned a3 = __float_as_uint(v.w) & 0x7fffffffu;
        local = max(local, max(max(a0, a1), max(a2, a3)));
    }
    #pragma unroll
    for (int off = 32; off > 0; off >>= 1)
        local = max(local, (unsigned)__shfl_down((int)local, off, 64));
    __shared__ unsigned smax[4];
    if ((threadIdx.x & 63) == 0) smax[threadIdx.x >> 6] = local;
    __syncthreads();
    if (threadIdx.x == 0) {
        unsigned m01 = max(smax[0], smax[1]);
        unsigned m23 = max(smax[2], smax[3]);
        atomicMax(out, max(m01, m23));
    }
}

// ---------------- quantize to int8 codes (exact ref op order) ----------------
__global__ void quant_kernel(const float* __restrict__ x, signed char* __restrict__ q,
                             long n16, const unsigned* __restrict__ amax_bits) {
    const float amax = fmaxf(__uint_as_float(*amax_bits), 1e-12f);
    const float s = FP8_MAX_F / amax;
    const long stride = (long)gridDim.x * blockDim.x;
    const float4* xv = (const float4*)x;
    int4* qv = (int4*)q;
    for (long i = (long)blockIdx.x * blockDim.x + threadIdx.x; i < n16; i += stride) {
        signed char c[16];
        #pragma unroll
        for (int j = 0; j < 4; ++j) {
            float4 v = xv[i * 4 + j];
            float e0 = v.x, e1 = v.y, e2 = v.z, e3 = v.w;
            float f0 = fminf(fmaxf(e0 * s, -FP8_MAX_F), FP8_MAX_F);
            float f1 = fminf(fmaxf(e1 * s, -FP8_MAX_F), FP8_MAX_F);
            float f2 = fminf(fmaxf(e2 * s, -FP8_MAX_F), FP8_MAX_F);
            float f3 = fminf(fmaxf(e3 * s, -FP8_MAX_F), FP8_MAX_F);
            c[j * 4 + 0] = (signed char)(int)rintf(f0 / FP8_MAX_F * 127.0f);
            c[j * 4 + 1] = (signed char)(int)rintf(f1 / FP8_MAX_F * 127.0f);
            c[j * 4 + 2] = (signed char)(int)rintf(f2 / FP8_MAX_F * 127.0f);
            c[j * 4 + 3] = (signed char)(int)rintf(f3 / FP8_MAX_F * 127.0f);
        }
        qv[i] = *(const int4*)c;
    }
}

// ---------------- int8 GEMM: C[m][n] = sum_k A[m][k]*B[n][k] ----------------
// 128x128 tile, BK=64, 256 threads = 4 waves (2x2), each wave 64x64 (4x4 frags
// of 16x16), mfma_i32_16x16x64_i8, global_load_lds width-16 staging.
__global__ __launch_bounds__(256) void gemm_i8_kernel(
    const signed char* __restrict__ A, const signed char* __restrict__ B,
    float* __restrict__ C, const unsigned* __restrict__ amax_bits)
{
    __shared__ signed char a_lds[128 * 64];
    __shared__ signed char b_lds[128 * 64];

    const int tid  = threadIdx.x;
    const int wid  = tid >> 6;
    const int lane = tid & 63;

    const long row0 = (long)blockIdx.x * 128;
    const long col0 = (long)blockIdx.y * 128;

    const int wr = (wid >> 1) * 64;   // wave row offset in tile
    const int wc = (wid & 1) * 64;    // wave col offset in tile

    i32x4 acc[4][4] = {};

    // staging: one global_load_lds issue = 64 lanes x 16B = 16 rows of 64B.
    // wave w covers rows [w*16, w*16+16) of each 64-row half.
    const int srow = lane >> 2;           // row within wave's 16-row group
    const int scol = (lane & 3) * 16;     // byte col within 64
    const long a_off = (row0 + wid * 16 + srow) * (long)K + scol;
    const long b_off = (col0 + wid * 16 + srow) * (long)K + scol;
    const signed char* aw0 = A + a_off;
    const signed char* aw1 = A + a_off + 64 * (long)K;
    const signed char* bw0 = B + b_off;
    const signed char* bw1 = B + b_off + 64 * (long)K;

    signed char* a_l0 = &a_lds[wid * 1024];
    signed char* a_l1 = &a_lds[4096 + wid * 1024];
    signed char* b_l0 = &b_lds[wid * 1024];
    signed char* b_l1 = &b_lds[4096 + wid * 1024];

    const int fr = lane & 15;     // fragment row/col within 16
    const int fq = lane >> 4;     // 0..3 quadrant

    for (int k0 = 0; k0 < K; k0 += 64) {
        __syncthreads();
        __builtin_amdgcn_global_load_lds(
            (const __attribute__((address_space(1))) void*)(aw0 + k0),
            (__attribute__((address_space(3))) void*)a_l0, 16, 0, 0);
        __builtin_amdgcn_global_load_lds(
            (const __attribute__((address_space(1))) void*)(aw1 + k0),
            (__attribute__((address_space(3))) void*)a_l1, 16, 0, 0);
        __builtin_amdgcn_global_load_lds(
            (const __attribute__((address_space(1))) void*)(bw0 + k0),
            (__attribute__((address_space(3))) void*)b_l0, 16, 0, 0);
        __builtin_amdgcn_global_load_lds(
            (const __attribute__((address_space(1))) void*)(bw1 + k0),
            (__attribute__((address_space(3))) void*)b_l1, 16, 0, 0);
        __syncthreads();

        i32x4 af[4], bf[4];
        #pragma unroll
        for (int mi = 0; mi < 4; ++mi)
            af[mi] = *(const i32x4*)&a_lds[(wr + mi * 16 + fr) * 64 + fq * 16];
        #pragma unroll
        for (int ni = 0; ni < 4; ++ni)
            bf[ni] = *(const i32x4*)&b_lds[(wc + ni * 16 + fr) * 64 + fq * 16];

        #pragma unroll
        for (int mi = 0; mi < 4; ++mi)
            #pragma unroll
            for (int ni = 0; ni < 4; ++ni)
                acc[mi][ni] = __builtin_amdgcn_mfma_i32_16x16x64_i8(
                    af[mi], bf[ni], acc[mi][ni], 0, 0, 0);
    }

    const float amax_x = fmaxf(__uint_as_float(amax_bits[0]), 1e-12f);
    const float amax_w = fmaxf(__uint_as_float(amax_bits[1]), 1e-12f);
    const float factor = amax_x * amax_w * (1.0f / (127.0f * 127.0f));

    #pragma unroll
    for (int mi = 0; mi < 4; ++mi) {
        #pragma unroll
        for (int ni = 0; ni < 4; ++ni) {
            const long col = col0 + wc + ni * 16 + fr;
            #pragma unroll
            for (int j = 0; j < 4; ++j) {
                const long row = row0 + wr + mi * 16 + fq * 4 + j;
                C[row * N + col] = (float)acc[mi][ni][j] * factor;
            }
        }
    }
}

extern "C" void kernel_launch(void* const* d_in, const int* in_sizes, int n_in,
                              void* d_out, int out_size, void* d_ws, size_t ws_size,
                              hipStream_t stream) {
    const float* x = (const float*)d_in[0];   // [4,2048,4096] -> [M,K]
    const float* w = (const float*)d_in[1];   // [N,K]
    float* out = (float*)d_out;               // [M,N]

    unsigned char* ws = (unsigned char*)d_ws;
    unsigned* amax = (unsigned*)ws;                        // 2 uints
    signed char* aq = (signed char*)(ws + 256);            // M*K int8
    signed char* wq = aq + (long)M * K;                    // N*K int8

    hipMemsetAsync(amax, 0, 2 * sizeof(unsigned), stream);

    const long nx = (long)M * K;
    const long nw = (long)N * K;
    amax_kernel<<<2048, 256, 0, stream>>>(x, nx / 4, &amax[0]);
    amax_kernel<<<2048, 256, 0, stream>>>(w, nw / 4, &amax[1]);
    quant_kernel<<<2048, 256, 0, stream>>>(x, aq, nx / 16, &amax[0]);
    quant_kernel<<<2048, 256, 0, stream>>>(w, wq, nw / 16, &amax[1]);

    dim3 grid(M / 128, N / 128);
    gemm_i8_kernel<<<grid, 256, 0, stream>>>(aq, wq, out, amax);
}

// Round 2
// 419.059 us; speedup vs baseline: 1.2106x; 1.2106x over previous
//
#include <hip/hip_runtime.h>

#define FP8_MAX_F 448.0f

static constexpr int M = 8192;   // 4*2048
static constexpr int N = 8192;
static constexpr int K = 4096;

typedef __attribute__((ext_vector_type(4))) int i32x4;

#define AS1 __attribute__((address_space(1)))
#define AS3 __attribute__((address_space(3)))
#define BARRIER() asm volatile("s_barrier" ::: "memory")
#define VMCNT(n)  asm volatile("s_waitcnt vmcnt(" #n ")" ::: "memory")

// ---------------- amax over both tensors (exact, bit-trick atomicMax) --------
__global__ void amax_kernel(const float* __restrict__ x, const float* __restrict__ w,
                            unsigned* __restrict__ out) {
    const long n4x = (long)M * K / 4;
    const long n4t = n4x + (long)N * K / 4;
    unsigned lx = 0u, lw = 0u;
    const long stride = (long)gridDim.x * blockDim.x;
    for (long i = (long)blockIdx.x * blockDim.x + threadIdx.x; i < n4t; i += stride) {
        if (i < n4x) {
            float4 v = ((const float4*)x)[i];
            unsigned a0 = __float_as_uint(v.x) & 0x7fffffffu;
            unsigned a1 = __float_as_uint(v.y) & 0x7fffffffu;
            unsigned a2 = __float_as_uint(v.z) & 0x7fffffffu;
            unsigned a3 = __float_as_uint(v.w) & 0x7fffffffu;
            lx = max(lx, max(max(a0, a1), max(a2, a3)));
        } else {
            float4 v = ((const float4*)w)[i - n4x];
            unsigned a0 = __float_as_uint(v.x) & 0x7fffffffu;
            unsigned a1 = __float_as_uint(v.y) & 0x7fffffffu;
            unsigned a2 = __float_as_uint(v.z) & 0x7fffffffu;
            unsigned a3 = __float_as_uint(v.w) & 0x7fffffffu;
            lw = max(lw, max(max(a0, a1), max(a2, a3)));
        }
    }
    #pragma unroll
    for (int off = 32; off > 0; off >>= 1) {
        lx = max(lx, (unsigned)__shfl_down((int)lx, off, 64));
        lw = max(lw, (unsigned)__shfl_down((int)lw, off, 64));
    }
    __shared__ unsigned smx[4], smw[4];
    if ((threadIdx.x & 63) == 0) { smx[threadIdx.x >> 6] = lx; smw[threadIdx.x >> 6] = lw; }
    __syncthreads();
    if (threadIdx.x == 0) {
        atomicMax(&out[0], max(max(smx[0], smx[1]), max(smx[2], smx[3])));
        atomicMax(&out[1], max(max(smw[0], smw[1]), max(smw[2], smw[3])));
    }
}

// ---------------- quantize both tensors to int8 codes, pre-swizzled layout ---
// Logical code for (row r, k) is stored with its 16B chunk XOR-permuted within
// each 64B k-group: out chunk = (k>>4)&3 XOR ((r>>1)&3). GEMM stages these 64B
// groups linearly into LDS (global_load_lds) and applies the same XOR on
// ds_read -> bank-conflict-free reads (T2, both-sides rule 21).
__device__ __forceinline__ signed char quant1(float v, float s) {
    float f = fminf(fmaxf(v * s, -FP8_MAX_F), FP8_MAX_F);
    return (signed char)(int)rintf(f / FP8_MAX_F * 127.0f);
}

__global__ void quant_kernel(const float* __restrict__ x, const float* __restrict__ w,
                             signed char* __restrict__ qx, signed char* __restrict__ qw,
                             const unsigned* __restrict__ amax_bits) {
    const float ax = fmaxf(__uint_as_float(amax_bits[0]), 1e-12f);
    const float aw = fmaxf(__uint_as_float(amax_bits[1]), 1e-12f);
    const float sxv = FP8_MAX_F / ax;
    const float swv = FP8_MAX_F / aw;
    const long cx = (long)M * K / 16;
    const long ct = cx + (long)N * K / 16;
    const long stride = (long)gridDim.x * blockDim.x;
    for (long ci = (long)blockIdx.x * blockDim.x + threadIdx.x; ci < ct; ci += stride) {
        const float* src; signed char* dst; float s; long c;
        if (ci < cx) { src = x; dst = qx; s = sxv; c = ci; }
        else         { src = w; dst = qw; s = swv; c = ci - cx; }
        const long r = c >> 8;              // K/16 = 256 chunks per row
        const int  cr = (int)(c & 255);
        const float4* in = (const float4*)(src + r * K + cr * 16);
        signed char ob[16];
        #pragma unroll
        for (int j = 0; j < 4; ++j) {
            float4 v = in[j];
            ob[j * 4 + 0] = quant1(v.x, s);
            ob[j * 4 + 1] = quant1(v.y, s);
            ob[j * 4 + 2] = quant1(v.z, s);
            ob[j * 4 + 3] = quant1(v.w, s);
        }
        const int osub = (cr & 3) ^ ((int)(r >> 1) & 3);
        *(int4*)(dst + r * K + ((long)((cr & ~3) + osub)) * 16) = *(const int4*)ob;
    }
}

// ---------------- int8 GEMM: C[m][n] = sum_k A[m][k]*B[n][k] ----------------
// 256x256 tile, BK=64, 512 threads = 8 waves (2M x 4N), wave output 128x64.
// 4-deep circular LDS buffer (4 x (A 16KB + B 16KB) = 128KB), counted vmcnt(4),
// raw s_barrier, setprio around MFMA clusters, swizzled ds_read (T2/T3/T4/T5).
__global__ __launch_bounds__(512, 2) void gemm_i8_kernel(
    const signed char* __restrict__ Aq, const signed char* __restrict__ Bq,
    float* __restrict__ C, const unsigned* __restrict__ amax_bits)
{
    __shared__ signed char lds[4][2][256 * 64];   // [buf][A/B][row*64 + col]

    const int tid  = threadIdx.x;
    const int wid  = tid >> 6;
    const int lane = tid & 63;
    const int wm = wid >> 2;          // 0..1  (M half)
    const int wn = wid & 3;           // 0..3  (N quarter)
    const int fr = lane & 15;
    const int fq = lane >> 4;

    const long row0 = (long)blockIdx.x * 256;
    const long col0 = (long)blockIdx.y * 256;

    const signed char* Ablk = Aq + row0 * K;
    const signed char* Bblk = Bq + col0 * K;

    // staging: one issue = 512 thr x 16B = 128 rows x 64B (linear LDS dest)
    const long stag_off = (long)(tid >> 2) * K + (long)(tid & 3) * 16;

    // swizzled ds_read offsets (swz constant across mi/ni since steps are x16)
    const int arow = wm * 128 + fr;
    const int aoff = arow * 64 + ((fq ^ ((arow >> 1) & 3)) * 16);
    const int brow = wn * 64 + fr;
    const int boff = brow * 64 + ((fq ^ ((brow >> 1) & 3)) * 16);

    i32x4 acc[8][4] = {};

#define STAGE(gbase, lbase) do { \
        __builtin_amdgcn_global_load_lds((const AS1 void*)((gbase) + stag_off), \
            (AS3 void*)((lbase) + wid * 1024), 16, 0, 0); \
        __builtin_amdgcn_global_load_lds((const AS1 void*)((gbase) + stag_off + 128L * K), \
            (AS3 void*)((lbase) + 8192 + wid * 1024), 16, 0, 0); \
    } while (0)

#define MFMA8(nb, bA, bB) do { \
        _Pragma("unroll") \
        for (int mi = 0; mi < 8; ++mi) { \
            acc[mi][nb]     = __builtin_amdgcn_mfma_i32_16x16x64_i8(af[mi], bA, acc[mi][nb], 0, 0, 0); \
            acc[mi][nb + 1] = __builtin_amdgcn_mfma_i32_16x16x64_i8(af[mi], bB, acc[mi][nb + 1], 0, 0, 0); \
        } \
    } while (0)

    // two phases per K-tile; VM_B (counted vmcnt) gates the NEXT tile's reads
#define TILE(bufi, STAGE_A_STMT, STAGE_B_STMT, VM_B_STMT) do { \
        const signed char* la = &lds[bufi][0][0]; \
        const signed char* lb = &lds[bufi][1][0]; \
        i32x4 af[8], b0, b1, b2, b3; \
        STAGE_A_STMT; \
        _Pragma("unroll") \
        for (int mi = 0; mi < 8; ++mi) \
            af[mi] = *(const i32x4*)(la + aoff + mi * 1024); \
        b0 = *(const i32x4*)(lb + boff + 0 * 1024); \
        b1 = *(const i32x4*)(lb + boff + 1 * 1024); \
        BARRIER(); \
        __builtin_amdgcn_s_setprio(1); \
        MFMA8(0, b0, b1); \
        __builtin_amdgcn_s_setprio(0); \
        BARRIER(); \
        STAGE_B_STMT; \
        b2 = *(const i32x4*)(lb + boff + 2 * 1024); \
        b3 = *(const i32x4*)(lb + boff + 3 * 1024); \
        VM_B_STMT; \
        BARRIER(); \
        __builtin_amdgcn_s_setprio(1); \
        MFMA8(2, b2, b3); \
        __builtin_amdgcn_s_setprio(0); \
        BARRIER(); \
    } while (0)

    // prologue: stage tiles 0 and 1 fully; wait tile 0 (8 issues -> 4 left)
    STAGE(Ablk + 0 * 64, &lds[0][0][0]);
    STAGE(Bblk + 0 * 64, &lds[0][1][0]);
    STAGE(Ablk + 1 * 64, &lds[1][0][0]);
    STAGE(Bblk + 1 * 64, &lds[1][1][0]);
    VMCNT(4);
    BARRIER();

    // main loop: tiles 0..61, staging tiles 2..63 (NT = 64)
    #pragma unroll 1
    for (int t = 0; t <= 60; t += 2) {
        TILE(t & 3,
             STAGE(Ablk + (t + 2) * 64, &lds[(t + 2) & 3][0][0]),
             STAGE(Bblk + (t + 2) * 64, &lds[(t + 2) & 3][1][0]),
             VMCNT(4));
        TILE((t + 1) & 3,
             STAGE(Ablk + (t + 3) * 64, &lds[(t + 3) & 3][0][0]),
             STAGE(Bblk + (t + 3) * 64, &lds[(t + 3) & 3][1][0]),
             VMCNT(4));
    }
    // epilogue: tile 62 (gated by last loop vmcnt), then tile 63 (vmcnt 0)
    TILE(2, (void)0, (void)0, VMCNT(0));
    TILE(3, (void)0, (void)0, (void)0);

#undef TILE
#undef MFMA8
#undef STAGE

    const float ax = fmaxf(__uint_as_float(amax_bits[0]), 1e-12f);
    const float aw = fmaxf(__uint_as_float(amax_bits[1]), 1e-12f);
    const float factor = ax * aw * (1.0f / (127.0f * 127.0f));

    #pragma unroll
    for (int mi = 0; mi < 8; ++mi) {
        #pragma unroll
        for (int ni = 0; ni < 4; ++ni) {
            const long col = col0 + wn * 64 + ni * 16 + fr;
            #pragma unroll
            for (int j = 0; j < 4; ++j) {
                const long row = row0 + wm * 128 + mi * 16 + fq * 4 + j;
                C[row * N + col] = (float)acc[mi][ni][j] * factor;
            }
        }
    }
}

extern "C" void kernel_launch(void* const* d_in, const int* in_sizes, int n_in,
                              void* d_out, int out_size, void* d_ws, size_t ws_size,
                              hipStream_t stream) {
    const float* x = (const float*)d_in[0];   // [4,2048,4096] -> [M,K]
    const float* w = (const float*)d_in[1];   // [N,K]
    float* out = (float*)d_out;               // [M,N]

    unsigned char* ws = (unsigned char*)d_ws;
    unsigned* amax = (unsigned*)ws;                        // 2 uints
    signed char* aq = (signed char*)(ws + 256);            // M*K int8 (swizzled)
    signed char* wq = aq + (long)M * K;                    // N*K int8 (swizzled)

    hipMemsetAsync(amax, 0, 2 * sizeof(unsigned), stream);
    amax_kernel<<<2048, 256, 0, stream>>>(x, w, amax);
    quant_kernel<<<4096, 256, 0, stream>>>(x, w, aq, wq, amax);

    dim3 grid(M / 256, N / 256);
    gemm_i8_kernel<<<grid, 512, 0, stream>>>(aq, wq, out, amax);
}